// Round 4
// baseline (208.529 us; speedup 1.0000x reference)
//
#include <hip/hip_runtime.h>
#include <math.h>

#define H 2048
#define L 350
#define G1 3072          // gh rows done in phase A (rest in phase B)
#define BAR_OFF 12288    // float offset of barrier state in ws (48 KB in)

__device__ __forceinline__ float dot4(float4 a, float4 b, float acc) {
    acc = fmaf(a.x, b.x, acc);
    acc = fmaf(a.y, b.y, acc);
    acc = fmaf(a.z, b.z, acc);
    acc = fmaf(a.w, b.w, acc);
    return acc;
}

__device__ __forceinline__ float wsum(float v) {
    #pragma unroll
    for (int m = 1; m < 64; m <<= 1) v += __shfl_xor(v, m, 64);
    return v;   // all lanes hold the sum
}
__device__ __forceinline__ float wmax(float v) {
    #pragma unroll
    for (int m = 1; m < 64; m <<= 1) v = fmaxf(v, __shfl_xor(v, m, 64));
    return v;
}

// Generation-counter grid barrier. Only thread 0 per block touches memory;
// cnt self-resets (last arriver), gen monotonically increases within a launch.
// Requires cnt==0 at launch (host memsets). s_sleep backoff keeps the fabric quiet.
__device__ __forceinline__ void grid_barrier(int* cnt, int* gen, int nb) {
    __syncthreads();
    if (threadIdx.x == 0) {
        __threadfence();   // publish this block's prior global writes
        const int g0 = __hip_atomic_load(gen, __ATOMIC_RELAXED, __HIP_MEMORY_SCOPE_AGENT);
        const int old = __hip_atomic_fetch_add(cnt, 1, __ATOMIC_ACQ_REL, __HIP_MEMORY_SCOPE_AGENT);
        if (old == nb - 1) {
            __hip_atomic_store(cnt, 0, __ATOMIC_RELAXED, __HIP_MEMORY_SCOPE_AGENT);
            __hip_atomic_fetch_add(gen, 1, __ATOMIC_RELEASE, __HIP_MEMORY_SCOPE_AGENT);
        } else {
            while (__hip_atomic_load(gen, __ATOMIC_ACQUIRE, __HIP_MEMORY_SCOPE_AGENT) == g0)
                __builtin_amdgcn_s_sleep(2);
        }
    }
    __syncthreads();
}

// ---- Phase A: attn logits (350 rows, 16KB) + gh rows [0, G1) (8KB each)
__device__ void phaseA(int b, int nb,
    const float4* x4, const float4* h4,
    const float* attn_W, const float* attn_b,
    const float* w_hh, const float* b_hh,
    float* logits, float* gh)
{
    const int w = threadIdx.x >> 6, lane = threadIdx.x & 63;
    const int nwaves = nb * 4;
    for (int item = b * 4 + w; item < L + G1; item += nwaves) {
        if (item < L) {
            const float4* Wr = reinterpret_cast<const float4*>(attn_W + (size_t)item * (2 * H));
            float acc = 0.f;
            #pragma unroll
            for (int i = lane; i < H / 4; i += 64) {
                acc = dot4(Wr[i], x4[i], acc);
                acc = dot4(Wr[H / 4 + i], h4[i], acc);
            }
            acc = wsum(acc);
            if (lane == 0) logits[item] = acc + attn_b[item];
        } else {
            const int row = item - L;
            const float4* Wr = reinterpret_cast<const float4*>(w_hh + (size_t)row * H);
            float acc = 0.f;
            #pragma unroll
            for (int i = lane; i < H / 4; i += 64) acc = dot4(Wr[i], h4[i], acc);
            acc = wsum(acc);
            if (lane == 0) gh[row] = acc + b_hh[row];
        }
    }
}

// ---- Phase B: blocks 0..7 softmax (redundant, deterministic) + context slice;
//      blocks 8.. finish gh rows [G1, 3H)
__device__ void phaseB(int b, int nb,
    const float4* h4, const float* enc,
    const float* w_hh, const float* b_hh,
    const float* logits, float* gh, float* ctx, float* attn_out)
{
    const int tid = threadIdx.x, w = tid >> 6, lane = tid & 63;
    if (b < 8) {
        __shared__ float attn_s[L];
        __shared__ float smax[4], ssum[4];
        float v0 = logits[tid];
        float v1 = (tid + 256 < L) ? logits[tid + 256] : -INFINITY;
        float m = wmax(fmaxf(v0, v1));
        if (lane == 0) smax[w] = m;
        __syncthreads();
        m = fmaxf(fmaxf(smax[0], smax[1]), fmaxf(smax[2], smax[3]));
        float e0 = expf(v0 - m);
        float e1 = (tid + 256 < L) ? expf(v1 - m) : 0.f;
        float s = wsum(e0 + e1);
        if (lane == 0) ssum[w] = s;
        __syncthreads();
        const float inv = 1.f / (ssum[0] + ssum[1] + ssum[2] + ssum[3]);
        attn_s[tid] = e0 * inv;
        if (tid + 256 < L) attn_s[tid + 256] = e1 * inv;
        if (b == 0) {
            attn_out[tid] = e0 * inv;
            if (tid + 256 < L) attn_out[tid + 256] = e1 * inv;
        }
        __syncthreads();
        const int i = b * 256 + tid;
        const float* ec = enc + i;
        float a0 = 0.f, a1 = 0.f, a2 = 0.f, a3 = 0.f;
        int j = 0;
        for (; j + 4 <= (L & ~3); j += 4) {
            a0 = fmaf(attn_s[j],     ec[(size_t)j * H],       a0);
            a1 = fmaf(attn_s[j + 1], ec[(size_t)(j + 1) * H], a1);
            a2 = fmaf(attn_s[j + 2], ec[(size_t)(j + 2) * H], a2);
            a3 = fmaf(attn_s[j + 3], ec[(size_t)(j + 3) * H], a3);
        }
        for (; j < L; ++j) a0 = fmaf(attn_s[j], ec[(size_t)j * H], a0);
        ctx[i] = (a0 + a1) + (a2 + a3);
    } else {
        const int nwaves = (nb - 8) * 4;
        for (int gwp = (b - 8) * 4 + w; gwp < 3 * H - G1; gwp += nwaves) {
            const int row = G1 + gwp;
            const float4* Wr = reinterpret_cast<const float4*>(w_hh + (size_t)row * H);
            float acc = 0.f;
            #pragma unroll
            for (int i = lane; i < H / 4; i += 64) acc = dot4(Wr[i], h4[i], acc);
            acc = wsum(acc);
            if (lane == 0) gh[row] = acc + b_hh[row];
        }
    }
}

// ---- Phase C: g = relu([x, ctx] @ comb_W.T + b), one wave per row
__device__ void phaseC(int b, int nb,
    const float4* x4, const float4* c4,
    const float* comb_W, const float* comb_b, float* g)
{
    const int w = threadIdx.x >> 6, lane = threadIdx.x & 63;
    const int nwaves = nb * 4;
    for (int r = b * 4 + w; r < H; r += nwaves) {
        const float4* Wr = reinterpret_cast<const float4*>(comb_W + (size_t)r * (2 * H));
        float acc = 0.f;
        #pragma unroll
        for (int i = lane; i < H / 4; i += 64) {
            acc = dot4(Wr[i], x4[i], acc);
            acc = dot4(Wr[H / 4 + i], c4[i], acc);
        }
        acc = wsum(acc);
        if (lane == 0) g[r] = fmaxf(acc + comb_b[r], 0.f);
    }
}

// ---- Phase D: gi GEMV (3 rows per item) + GRU gates, one wave per item
__device__ void phaseD(int b, int nb,
    const float4* g4, const float* hidden,
    const float* w_ih, const float* b_ih,
    const float* gh, float* out)
{
    const int w = threadIdx.x >> 6, lane = threadIdx.x & 63;
    const int nwaves = nb * 4;
    for (int item = b * 4 + w; item < H; item += nwaves) {
        const float4* Wr0 = reinterpret_cast<const float4*>(w_ih + (size_t)item * H);
        const float4* Wr1 = reinterpret_cast<const float4*>(w_ih + (size_t)(item + H) * H);
        const float4* Wr2 = reinterpret_cast<const float4*>(w_ih + (size_t)(item + 2 * H) * H);
        float ar = 0.f, az = 0.f, an = 0.f;
        #pragma unroll
        for (int i = lane; i < H / 4; i += 64) {
            const float4 gv = g4[i];
            ar = dot4(Wr0[i], gv, ar);
            az = dot4(Wr1[i], gv, az);
            an = dot4(Wr2[i], gv, an);
        }
        ar = wsum(ar); az = wsum(az); an = wsum(an);
        if (lane == 0) {
            const float ir  = ar + b_ih[item];
            const float iz  = az + b_ih[item + H];
            const float in_ = an + b_ih[item + 2 * H];
            const float r = 1.f / (1.f + expf(-(ir + gh[item])));
            const float z = 1.f / (1.f + expf(-(iz + gh[item + H])));
            const float n = tanhf(in_ + r * gh[item + 2 * H]);
            const float hnew = (1.f - z) * n + z * hidden[item];
            out[item] = hnew;
            out[H + item] = hnew;
        }
    }
}

__global__ __launch_bounds__(256, 4) void fused_decoder_kernel(
    const float* __restrict__ input, const float* __restrict__ hidden,
    const float* __restrict__ enc,
    const float* __restrict__ attn_W, const float* __restrict__ attn_b,
    const float* __restrict__ comb_W, const float* __restrict__ comb_b,
    const float* __restrict__ w_ih, const float* __restrict__ w_hh,
    const float* __restrict__ b_ih, const float* __restrict__ b_hh,
    float* __restrict__ out, float* __restrict__ ws)
{
    float* logits = ws;            // 350
    float* gh     = ws + 512;      // 6144
    float* g      = ws + 7168;     // 2048
    float* ctx    = ws + 9216;     // 2048
    int*   cnt    = (int*)(ws + BAR_OFF);
    int*   gen    = (int*)(ws + BAR_OFF + 32);

    const int b = blockIdx.x, nb = gridDim.x;
    const float4* x4 = reinterpret_cast<const float4*>(input);
    const float4* h4 = reinterpret_cast<const float4*>(hidden);

    phaseA(b, nb, x4, h4, attn_W, attn_b, w_hh, b_hh, logits, gh);
    grid_barrier(cnt, gen, nb);
    phaseB(b, nb, h4, enc, w_hh, b_hh, logits, gh, ctx, out + 2 * H);
    grid_barrier(cnt, gen, nb);
    phaseC(b, nb, x4, reinterpret_cast<const float4*>(ctx), comb_W, comb_b, g);
    grid_barrier(cnt, gen, nb);
    phaseD(b, nb, reinterpret_cast<const float4*>(g), hidden, w_ih, b_ih, gh, out);
}

extern "C" void kernel_launch(void* const* d_in, const int* in_sizes, int n_in,
                              void* d_out, int out_size, void* d_ws, size_t ws_size,
                              hipStream_t stream)
{
    const float* input  = (const float*)d_in[0];
    const float* hidden = (const float*)d_in[1];
    const float* enc    = (const float*)d_in[2];
    const float* attn_W = (const float*)d_in[3];
    const float* attn_b = (const float*)d_in[4];
    const float* comb_W = (const float*)d_in[5];
    const float* comb_b = (const float*)d_in[6];
    const float* w_ih   = (const float*)d_in[7];
    const float* w_hh   = (const float*)d_in[8];
    const float* b_ih   = (const float*)d_in[9];
    const float* b_hh   = (const float*)d_in[10];
    float* out = (float*)d_out;
    float* ws  = (float*)d_ws;

    // Co-residency: pick blocks/CU from the runtime's own occupancy arithmetic,
    // capped at 4 (1024 blocks). Deterministic; no cooperative-launch validation.
    int per = 0;
    if (hipOccupancyMaxActiveBlocksPerMultiprocessor(
            &per, (const void*)fused_decoder_kernel, 256, 0) != hipSuccess || per < 1)
        per = 2;
    if (per > 4) per = 4;
    const int nb = per * 256;

    // Barrier state must be zero at kernel start (ws is poisoned 0xAA once).
    hipMemsetAsync(ws + BAR_OFF, 0, 256, stream);

    fused_decoder_kernel<<<nb, 256, 0, stream>>>(
        input, hidden, enc, attn_W, attn_b, comb_W, comb_b,
        w_ih, w_hh, b_ih, b_hh, out, ws);
}

// Round 5
// 38.433 us; speedup vs baseline: 5.4258x; 5.4258x over previous
//
#include <hip/hip_runtime.h>
#include <math.h>

#define H 2048
#define L 350

__device__ __forceinline__ float dot4(float4 a, float4 b, float acc) {
    acc = fmaf(a.x, b.x, acc);
    acc = fmaf(a.y, b.y, acc);
    acc = fmaf(a.z, b.z, acc);
    acc = fmaf(a.w, b.w, acc);
    return acc;
}

__device__ __forceinline__ float wsum(float v) {
    #pragma unroll
    for (int m = 1; m < 64; m <<= 1) v += __shfl_xor(v, m, 64);
    return v;
}
__device__ __forceinline__ float wmax(float v) {
    #pragma unroll
    for (int m = 1; m < 64; m <<= 1) v = fmaxf(v, __shfl_xor(v, m, 64));
    return v;
}

// K1: one wave per row. Rows [0,350): attn logits (16KB rows).
//     Rows [350, 350+6144): gh = h @ w_hh.T + b_hh (8KB rows).
__global__ __launch_bounds__(256) void k1_logits_gh(
    const float* __restrict__ input, const float* __restrict__ hidden,
    const float* __restrict__ attn_W, const float* __restrict__ attn_b,
    const float* __restrict__ w_hh, const float* __restrict__ b_hh,
    float* __restrict__ logits, float* __restrict__ gh)
{
    const int w = threadIdx.x >> 6, lane = threadIdx.x & 63;
    const int item = blockIdx.x * 4 + w;
    const float4* x4 = reinterpret_cast<const float4*>(input);
    const float4* h4 = reinterpret_cast<const float4*>(hidden);
    if (item < L) {
        const float4* Wr = reinterpret_cast<const float4*>(attn_W + (size_t)item * (2 * H));
        float acc = 0.f;
        #pragma unroll
        for (int i = lane; i < H / 4; i += 64) {
            acc = dot4(Wr[i], x4[i], acc);
            acc = dot4(Wr[H / 4 + i], h4[i], acc);
        }
        acc = wsum(acc);
        if (lane == 0) logits[item] = acc + attn_b[item];
    } else if (item < L + 3 * H) {
        const int row = item - L;
        const float4* Wr = reinterpret_cast<const float4*>(w_hh + (size_t)row * H);
        float acc = 0.f;
        #pragma unroll
        for (int i = lane; i < H / 4; i += 64) acc = dot4(Wr[i], h4[i], acc);
        acc = wsum(acc);
        if (lane == 0) gh[row] = acc + b_hh[row];
    }
}

// K2: softmax over 350 logits (computed redundantly per block, deterministic)
//     + context GEMV. 64 blocks; block handles 32 columns; 8 threads per
//     column split over rows (stride-8), 4-deep ILP; LDS reduce.
__global__ __launch_bounds__(256) void k2_softmax_ctx(
    const float* __restrict__ logits, const float* __restrict__ enc,
    float* __restrict__ ctx, float* __restrict__ attn_out)
{
    __shared__ float attn_s[L];
    __shared__ float smax[4], ssum[4];
    __shared__ float partial[8][32];
    const int t = threadIdx.x, w = t >> 6, lane = t & 63;

    float v0 = (t < L) ? logits[t] : -INFINITY;
    float v1 = (t + 256 < L) ? logits[t + 256] : -INFINITY;
    float m = wmax(fmaxf(v0, v1));
    if (lane == 0) smax[w] = m;
    __syncthreads();
    m = fmaxf(fmaxf(smax[0], smax[1]), fmaxf(smax[2], smax[3]));
    float e0 = (t < L) ? expf(v0 - m) : 0.f;
    float e1 = (t + 256 < L) ? expf(v1 - m) : 0.f;
    float s = wsum(e0 + e1);
    if (lane == 0) ssum[w] = s;
    __syncthreads();
    const float inv = 1.f / (ssum[0] + ssum[1] + ssum[2] + ssum[3]);
    if (t < L) attn_s[t] = e0 * inv;
    if (t + 256 < L) attn_s[t + 256] = e1 * inv;
    if (blockIdx.x == 0) {
        if (t < L) attn_out[t] = e0 * inv;
        if (t + 256 < L) attn_out[t + 256] = e1 * inv;
    }
    __syncthreads();

    // context: col = blockIdx*32 + (t&31); row stream k + 8*m, k = t>>5
    const int col_l = t & 31, k = t >> 5;
    const int col = blockIdx.x * 32 + col_l;
    const float* ec = enc + col;
    float a0 = 0.f, a1 = 0.f, a2 = 0.f, a3 = 0.f;
    int j = k;
    for (; j + 24 < L; j += 32) {
        a0 = fmaf(attn_s[j],      ec[(size_t)j * H],        a0);
        a1 = fmaf(attn_s[j + 8],  ec[(size_t)(j + 8) * H],  a1);
        a2 = fmaf(attn_s[j + 16], ec[(size_t)(j + 16) * H], a2);
        a3 = fmaf(attn_s[j + 24], ec[(size_t)(j + 24) * H], a3);
    }
    for (; j < L; j += 8) a0 = fmaf(attn_s[j], ec[(size_t)j * H], a0);
    partial[k][col_l] = (a0 + a1) + (a2 + a3);
    __syncthreads();
    if (t < 32) {
        float acc = 0.f;
        #pragma unroll
        for (int kk = 0; kk < 8; ++kk) acc += partial[kk][t];
        ctx[blockIdx.x * 32 + t] = acc;
    }
}

// K3: g = relu([x, ctx] @ comb_W.T + b), one wave per row (16KB rows)
__global__ __launch_bounds__(256) void k3_combine(
    const float* __restrict__ input, const float* __restrict__ ctx,
    const float* __restrict__ comb_W, const float* __restrict__ comb_b,
    float* __restrict__ g)
{
    const int w = threadIdx.x >> 6, lane = threadIdx.x & 63;
    const int r = blockIdx.x * 4 + w;
    const float4* x4 = reinterpret_cast<const float4*>(input);
    const float4* c4 = reinterpret_cast<const float4*>(ctx);
    const float4* Wr = reinterpret_cast<const float4*>(comb_W + (size_t)r * (2 * H));
    float acc = 0.f;
    #pragma unroll
    for (int i = lane; i < H / 4; i += 64) {
        acc = dot4(Wr[i], x4[i], acc);
        acc = dot4(Wr[H / 4 + i], c4[i], acc);
    }
    acc = wsum(acc);
    if (lane == 0) g[r] = fmaxf(acc + comb_b[r], 0.f);
}

// K4: gi = g @ w_ih.T + b_ih (3 rows per item) + GRU gates, one wave per item
__global__ __launch_bounds__(256) void k4_gru(
    const float* __restrict__ g, const float* __restrict__ hidden,
    const float* __restrict__ w_ih, const float* __restrict__ b_ih,
    const float* __restrict__ gh, float* __restrict__ out)
{
    const int w = threadIdx.x >> 6, lane = threadIdx.x & 63;
    const int item = blockIdx.x * 4 + w;
    const float4* g4 = reinterpret_cast<const float4*>(g);
    const float4* Wr0 = reinterpret_cast<const float4*>(w_ih + (size_t)item * H);
    const float4* Wr1 = reinterpret_cast<const float4*>(w_ih + (size_t)(item + H) * H);
    const float4* Wr2 = reinterpret_cast<const float4*>(w_ih + (size_t)(item + 2 * H) * H);
    float ar = 0.f, az = 0.f, an = 0.f;
    #pragma unroll
    for (int i = lane; i < H / 4; i += 64) {
        const float4 gv = g4[i];
        ar = dot4(Wr0[i], gv, ar);
        az = dot4(Wr1[i], gv, az);
        an = dot4(Wr2[i], gv, an);
    }
    ar = wsum(ar); az = wsum(az); an = wsum(an);
    if (lane == 0) {
        const float ir  = ar + b_ih[item];
        const float iz  = az + b_ih[item + H];
        const float in_ = an + b_ih[item + 2 * H];
        const float r = 1.f / (1.f + expf(-(ir + gh[item])));
        const float z = 1.f / (1.f + expf(-(iz + gh[item + H])));
        const float n = tanhf(in_ + r * gh[item + 2 * H]);
        const float hnew = (1.f - z) * n + z * hidden[item];
        out[item] = hnew;
        out[H + item] = hnew;
    }
}

extern "C" void kernel_launch(void* const* d_in, const int* in_sizes, int n_in,
                              void* d_out, int out_size, void* d_ws, size_t ws_size,
                              hipStream_t stream)
{
    const float* input  = (const float*)d_in[0];
    const float* hidden = (const float*)d_in[1];
    const float* enc    = (const float*)d_in[2];
    const float* attn_W = (const float*)d_in[3];
    const float* attn_b = (const float*)d_in[4];
    const float* comb_W = (const float*)d_in[5];
    const float* comb_b = (const float*)d_in[6];
    const float* w_ih   = (const float*)d_in[7];
    const float* w_hh   = (const float*)d_in[8];
    const float* b_ih   = (const float*)d_in[9];
    const float* b_hh   = (const float*)d_in[10];
    float* out = (float*)d_out;
    float* ws  = (float*)d_ws;

    float* logits = ws;            // 350
    float* gh     = ws + 512;      // 6144
    float* g      = ws + 7168;     // 2048
    float* ctx    = ws + 9216;     // 2048

    k1_logits_gh<<<(L + 3 * H + 3) / 4, 256, 0, stream>>>(
        input, hidden, attn_W, attn_b, w_hh, b_hh, logits, gh);
    k2_softmax_ctx<<<64, 256, 0, stream>>>(logits, enc, ctx, out + 2 * H);
    k3_combine<<<H / 4, 256, 0, stream>>>(input, ctx, comb_W, comb_b, g);
    k4_gru<<<H / 4, 256, 0, stream>>>(g, hidden, w_ih, b_ih, gh, out);
}

// Round 6
// 37.572 us; speedup vs baseline: 5.5500x; 1.0229x over previous
//
#include <hip/hip_runtime.h>
#include <math.h>

#define H 2048
#define L 350
#define GH1 4096         // gh rows computed in K1; rest (2048) in K2

__device__ __forceinline__ float dot4(float4 a, float4 b, float acc) {
    acc = fmaf(a.x, b.x, acc);
    acc = fmaf(a.y, b.y, acc);
    acc = fmaf(a.z, b.z, acc);
    acc = fmaf(a.w, b.w, acc);
    return acc;
}

__device__ __forceinline__ float wsum(float v) {
    #pragma unroll
    for (int m = 1; m < 64; m <<= 1) v += __shfl_xor(v, m, 64);
    return v;
}
__device__ __forceinline__ float wmax(float v) {
    #pragma unroll
    for (int m = 1; m < 64; m <<= 1) v = fmaxf(v, __shfl_xor(v, m, 64));
    return v;
}

// gh row helper: gh[row] = h . w_hh[row] + b_hh[row], one wave
__device__ __forceinline__ void gh_row(int row, int lane,
    const float4* h4, const float* w_hh, const float* b_hh, float* gh)
{
    const float4* Wr = reinterpret_cast<const float4*>(w_hh + (size_t)row * H);
    float acc = 0.f;
    #pragma unroll
    for (int i = lane; i < H / 4; i += 64) acc = dot4(Wr[i], h4[i], acc);
    acc = wsum(acc);
    if (lane == 0) gh[row] = acc + b_hh[row];
}

// K1: waves 0..349: attn logits (16KB rows); waves 350..350+GH1: gh rows [0,GH1)
__global__ __launch_bounds__(256) void k1_logits_gh(
    const float* __restrict__ input, const float* __restrict__ hidden,
    const float* __restrict__ attn_W, const float* __restrict__ attn_b,
    const float* __restrict__ w_hh, const float* __restrict__ b_hh,
    float* __restrict__ logits, float* __restrict__ gh)
{
    const int w = threadIdx.x >> 6, lane = threadIdx.x & 63;
    const int item = blockIdx.x * 4 + w;
    const float4* x4 = reinterpret_cast<const float4*>(input);
    const float4* h4 = reinterpret_cast<const float4*>(hidden);
    if (item < L) {
        const float4* Wr = reinterpret_cast<const float4*>(attn_W + (size_t)item * (2 * H));
        float acc = 0.f;
        #pragma unroll
        for (int i = lane; i < H / 4; i += 64) {
            acc = dot4(Wr[i], x4[i], acc);
            acc = dot4(Wr[H / 4 + i], h4[i], acc);
        }
        acc = wsum(acc);
        if (lane == 0) logits[item] = acc + attn_b[item];
    } else if (item < L + GH1) {
        gh_row(item - L, lane, h4, w_hh, b_hh, gh);
    }
}

// K2: blocks 0..63: softmax (redundant per block, deterministic) + 32 ctx cols;
//     blocks 64..575: gh rows [GH1, 6144)
__global__ __launch_bounds__(256) void k2_softmax_ctx_gh(
    const float* __restrict__ logits, const float* __restrict__ enc,
    const float* __restrict__ hidden,
    const float* __restrict__ w_hh, const float* __restrict__ b_hh,
    float* __restrict__ ctx, float* __restrict__ gh, float* __restrict__ attn_out)
{
    const int t = threadIdx.x, w = t >> 6, lane = t & 63;
    if (blockIdx.x >= 64) {
        const int row = GH1 + (blockIdx.x - 64) * 4 + w;
        gh_row(row, lane, reinterpret_cast<const float4*>(hidden), w_hh, b_hh, gh);
        return;
    }
    __shared__ float attn_s[L];
    __shared__ float smax[4], ssum[4];
    __shared__ float partial[8][32];

    float v0 = (t < L) ? logits[t] : -INFINITY;
    float v1 = (t + 256 < L) ? logits[t + 256] : -INFINITY;
    float m = wmax(fmaxf(v0, v1));
    if (lane == 0) smax[w] = m;
    __syncthreads();
    m = fmaxf(fmaxf(smax[0], smax[1]), fmaxf(smax[2], smax[3]));
    float e0 = (t < L) ? expf(v0 - m) : 0.f;
    float e1 = (t + 256 < L) ? expf(v1 - m) : 0.f;
    float s = wsum(e0 + e1);
    if (lane == 0) ssum[w] = s;
    __syncthreads();
    const float inv = 1.f / (ssum[0] + ssum[1] + ssum[2] + ssum[3]);
    if (t < L) attn_s[t] = e0 * inv;
    if (t + 256 < L) attn_s[t + 256] = e1 * inv;
    if (blockIdx.x == 0) {
        if (t < L) attn_out[t] = e0 * inv;
        if (t + 256 < L) attn_out[t + 256] = e1 * inv;
    }
    __syncthreads();

    // ctx: col = blockIdx*32 + (t&31); 8-way row split (k = t>>5), 4-deep ILP
    const int col_l = t & 31, k = t >> 5;
    const int col = blockIdx.x * 32 + col_l;
    const float* ec = enc + col;
    float a0 = 0.f, a1 = 0.f, a2 = 0.f, a3 = 0.f;
    int j = k;
    for (; j + 24 < L; j += 32) {
        a0 = fmaf(attn_s[j],      ec[(size_t)j * H],        a0);
        a1 = fmaf(attn_s[j + 8],  ec[(size_t)(j + 8) * H],  a1);
        a2 = fmaf(attn_s[j + 16], ec[(size_t)(j + 16) * H], a2);
        a3 = fmaf(attn_s[j + 24], ec[(size_t)(j + 24) * H], a3);
    }
    for (; j < L; j += 8) a0 = fmaf(attn_s[j], ec[(size_t)j * H], a0);
    partial[k][col_l] = (a0 + a1) + (a2 + a3);
    __syncthreads();
    if (t < 32) {
        float acc = 0.f;
        #pragma unroll
        for (int kk = 0; kk < 8; ++kk) acc += partial[kk][t];
        ctx[blockIdx.x * 32 + t] = acc;
    }
}

// K3: g = relu([x, ctx] @ comb_W.T + b), one wave per row (16KB rows)
__global__ __launch_bounds__(256) void k3_combine(
    const float* __restrict__ input, const float* __restrict__ ctx,
    const float* __restrict__ comb_W, const float* __restrict__ comb_b,
    float* __restrict__ g)
{
    const int w = threadIdx.x >> 6, lane = threadIdx.x & 63;
    const int r = blockIdx.x * 4 + w;
    const float4* x4 = reinterpret_cast<const float4*>(input);
    const float4* c4 = reinterpret_cast<const float4*>(ctx);
    const float4* Wr = reinterpret_cast<const float4*>(comb_W + (size_t)r * (2 * H));
    float acc = 0.f;
    #pragma unroll
    for (int i = lane; i < H / 4; i += 64) {
        acc = dot4(Wr[i], x4[i], acc);
        acc = dot4(Wr[H / 4 + i], c4[i], acc);
    }
    acc = wsum(acc);
    if (lane == 0) g[r] = fmaxf(acc + comb_b[r], 0.f);
}

// K4: gi = g @ w_ih.T + b_ih (3 rows per item) + GRU gates, one wave per item
__global__ __launch_bounds__(256) void k4_gru(
    const float* __restrict__ g, const float* __restrict__ hidden,
    const float* __restrict__ w_ih, const float* __restrict__ b_ih,
    const float* __restrict__ gh, float* __restrict__ out)
{
    const int w = threadIdx.x >> 6, lane = threadIdx.x & 63;
    const int item = blockIdx.x * 4 + w;
    const float4* g4 = reinterpret_cast<const float4*>(g);
    const float4* Wr0 = reinterpret_cast<const float4*>(w_ih + (size_t)item * H);
    const float4* Wr1 = reinterpret_cast<const float4*>(w_ih + (size_t)(item + H) * H);
    const float4* Wr2 = reinterpret_cast<const float4*>(w_ih + (size_t)(item + 2 * H) * H);
    float ar = 0.f, az = 0.f, an = 0.f;
    #pragma unroll
    for (int i = lane; i < H / 4; i += 64) {
        const float4 gv = g4[i];
        ar = dot4(Wr0[i], gv, ar);
        az = dot4(Wr1[i], gv, az);
        an = dot4(Wr2[i], gv, an);
    }
    ar = wsum(ar); az = wsum(az); an = wsum(an);
    if (lane == 0) {
        const float ir  = ar + b_ih[item];
        const float iz  = az + b_ih[item + H];
        const float in_ = an + b_ih[item + 2 * H];
        const float r = 1.f / (1.f + expf(-(ir + gh[item])));
        const float z = 1.f / (1.f + expf(-(iz + gh[item + H])));
        const float n = tanhf(in_ + r * gh[item + 2 * H]);
        const float hnew = (1.f - z) * n + z * hidden[item];
        out[item] = hnew;
        out[H + item] = hnew;
    }
}

extern "C" void kernel_launch(void* const* d_in, const int* in_sizes, int n_in,
                              void* d_out, int out_size, void* d_ws, size_t ws_size,
                              hipStream_t stream)
{
    const float* input  = (const float*)d_in[0];
    const float* hidden = (const float*)d_in[1];
    const float* enc    = (const float*)d_in[2];
    const float* attn_W = (const float*)d_in[3];
    const float* attn_b = (const float*)d_in[4];
    const float* comb_W = (const float*)d_in[5];
    const float* comb_b = (const float*)d_in[6];
    const float* w_ih   = (const float*)d_in[7];
    const float* w_hh   = (const float*)d_in[8];
    const float* b_ih   = (const float*)d_in[9];
    const float* b_hh   = (const float*)d_in[10];
    float* out = (float*)d_out;
    float* ws  = (float*)d_ws;

    float* logits = ws;            // 350
    float* gh     = ws + 512;      // 6144
    float* g      = ws + 7168;     // 2048
    float* ctx    = ws + 9216;     // 2048

    k1_logits_gh<<<(L + GH1 + 3) / 4, 256, 0, stream>>>(
        input, hidden, attn_W, attn_b, w_hh, b_hh, logits, gh);
    k2_softmax_ctx_gh<<<64 + (3 * H - GH1) / 4, 256, 0, stream>>>(
        logits, enc, hidden, w_hh, b_hh, ctx, gh, out + 2 * H);
    k3_combine<<<H / 4, 256, 0, stream>>>(input, ctx, comb_W, comb_b, g);
    k4_gru<<<H / 4, 256, 0, stream>>>(g, hidden, w_ih, b_ih, gh, out);
}